// Round 1
// baseline (74.633 us; speedup 1.0000x reference)
//
#include <hip/hip_runtime.h>
#include <math.h>

#define D_DIM 1280
#define ODIM  510

typedef short bf16x8 __attribute__((ext_vector_type(8)));   // 8 bf16 = 4 VGPRs
typedef float f32x4  __attribute__((ext_vector_type(4)));

// pack two fp32 -> packed bf16 pair (round-half-up) — same rounding as prior version
__device__ __forceinline__ unsigned pkbf(float a, float b) {
  unsigned ua = __float_as_uint(a), ub = __float_as_uint(b);
  return ((ua + 0x8000u) >> 16) | ((ub + 0x8000u) & 0xffff0000u);
}

union B8 { unsigned u[4]; bf16x8 v; };

// Fully fused: out[i,j,k] = sum_d X[i+1,d]*X[j+1,d]*Wp[d,k] + b[k]  (symmetrized
// diff term cancels). One block per upper-triangle 16x16 tile (528 blocks).
// Fragments are gathered DIRECTLY from X (L2-resident, 2.6 MB) — no prep kernel,
// no workspace, no bf16-plane round trip. 4 waves split K into quarters of 320;
// per K-step a lane loads its 32B row-chunk of X (A and B side) + 64B of W
// (quad-uniform -> broadcast), multiplies, packs bf16, feeds 2 MFMAs.
__global__ __launch_bounds__(256, 2) void pcmd_fused(
    const float* __restrict__ X,        // [512][1280]
    const float* __restrict__ W,        // [2560][2] (first 1280 rows = Wp)
    const float* __restrict__ bias,     // [2]
    float* __restrict__ out)            // [510][510][2]
{
  __shared__ float sR[4][2][16][17];

  // upper-triangle decode: block t -> (bi, bj), bi <= bj
  const int t = (int)blockIdx.x;
  int bi = (int)((65.0 - sqrt(4225.0 - 8.0 * (double)t)) * 0.5);
  {
    int s0 = bi * 32 - (bi * (bi - 1)) / 2;
    if (t < s0) { --bi; }
    int s1 = (bi + 1) * 32 - ((bi + 1) * bi) / 2;
    if (t >= s1) { ++bi; }
  }
  const int start = bi * 32 - (bi * (bi - 1)) / 2;
  const int bj = bi + (t - start);

  const int tid  = threadIdx.x;
  const int lane = tid & 63;
  const int wv   = tid >> 6;            // K-quarter 0..3
  const int m    = lane & 15;
  const int quad = lane >> 4;

  // plane row r corresponds to X row r+1 (the [1:-1] crop). Rows >= 510 of the
  // 512-row tile space are store-guarded, so clamping to X row 511 is safe
  // (branchless, no OOB, garbage confined to discarded C rows/cols).
  const int rA = min(bi * 16 + m + 1, 511);
  const int rB = min(bj * 16 + m + 1, 511);
  const int kq = wv * 320 + quad * 8;   // this lane's k-base within its quarter
  const float* __restrict__ pa = X + (size_t)rA * D_DIM + kq;
  const float* __restrict__ pb = X + (size_t)rB * D_DIM + kq;
  const float* __restrict__ pw = W + 2 * kq;

  f32x4 acc0 = {0.f, 0.f, 0.f, 0.f};
  f32x4 acc1 = {0.f, 0.f, 0.f, 0.f};

  // depth-2 prefetch pipeline over the 10 K-steps of this wave's quarter
  float4 xa0[2], xa1[2], xb0[2], xb1[2], w0[2], w1[2], w2[2], w3[2];

  xa0[0] = *(const float4*)(pa + 0);   xa1[0] = *(const float4*)(pa + 4);
  xb0[0] = *(const float4*)(pb + 0);   xb1[0] = *(const float4*)(pb + 4);
  w0[0]  = *(const float4*)(pw + 0);   w1[0]  = *(const float4*)(pw + 4);
  w2[0]  = *(const float4*)(pw + 8);   w3[0]  = *(const float4*)(pw + 12);

  #pragma unroll
  for (int s = 0; s < 10; ++s) {
    const int cur = s & 1, nxt = cur ^ 1;
    if (s < 9) {
      const int o = (s + 1) * 32;       // compile-time after unroll -> imm offsets
      xa0[nxt] = *(const float4*)(pa + o);          xa1[nxt] = *(const float4*)(pa + o + 4);
      xb0[nxt] = *(const float4*)(pb + o);          xb1[nxt] = *(const float4*)(pb + o + 4);
      w0[nxt]  = *(const float4*)(pw + 2 * o);      w1[nxt]  = *(const float4*)(pw + 2 * o + 4);
      w2[nxt]  = *(const float4*)(pw + 2 * o + 8);  w3[nxt]  = *(const float4*)(pw + 2 * o + 12);
    }
    const float4 xA0 = xa0[cur], xA1 = xa1[cur];
    const float4 xB0 = xb0[cur], xB1 = xb1[cur];
    const float4 W0 = w0[cur], W1 = w1[cur], W2 = w2[cur], W3 = w3[cur];

    B8 fb, fa0, fa1;
    // B fragment: raw X (col side)
    fb.u[0] = pkbf(xB0.x, xB0.y);  fb.u[1] = pkbf(xB0.z, xB0.w);
    fb.u[2] = pkbf(xB1.x, xB1.y);  fb.u[3] = pkbf(xB1.z, xB1.w);
    // A fragments: X * Wp[:,0] and X * Wp[:,1] (row side)
    fa0.u[0] = pkbf(xA0.x * W0.x, xA0.y * W0.z);  fa0.u[1] = pkbf(xA0.z * W1.x, xA0.w * W1.z);
    fa0.u[2] = pkbf(xA1.x * W2.x, xA1.y * W2.z);  fa0.u[3] = pkbf(xA1.z * W3.x, xA1.w * W3.z);
    fa1.u[0] = pkbf(xA0.x * W0.y, xA0.y * W0.w);  fa1.u[1] = pkbf(xA0.z * W1.y, xA0.w * W1.w);
    fa1.u[2] = pkbf(xA1.x * W2.y, xA1.y * W2.w);  fa1.u[3] = pkbf(xA1.z * W3.y, xA1.w * W3.w);

    acc0 = __builtin_amdgcn_mfma_f32_16x16x32_bf16(fa0.v, fb.v, acc0, 0, 0, 0);
    acc1 = __builtin_amdgcn_mfma_f32_16x16x32_bf16(fa1.v, fb.v, acc1, 0, 0, 0);
  }

  // split-K reduce across the 4 waves via LDS (same as verified prior version)
  #pragma unroll
  for (int r = 0; r < 4; ++r) {
    sR[wv][0][quad * 4 + r][m] = acc0[r];
    sR[wv][1][quad * 4 + r][m] = acc1[r];
  }
  __syncthreads();

  const float b0 = bias[0], b1 = bias[1];
  const int il = tid >> 4, jl = tid & 15;

  {
    const int oi = bi * 16 + il, oj = bj * 16 + jl;
    if (oi < ODIM && oj < ODIM) {
      float2 v;
      v.x = sR[0][0][il][jl] + sR[1][0][il][jl] + sR[2][0][il][jl] + sR[3][0][il][jl] + b0;
      v.y = sR[0][1][il][jl] + sR[1][1][il][jl] + sR[2][1][il][jl] + sR[3][1][il][jl] + b1;
      *(float2*)(out + ((size_t)oi * ODIM + oj) * 2) = v;
    }
  }
  if (bi != bj) {
    const int oi = bj * 16 + il, oj = bi * 16 + jl;
    if (oi < ODIM && oj < ODIM) {
      float2 v;
      v.x = sR[0][0][jl][il] + sR[1][0][jl][il] + sR[2][0][jl][il] + sR[3][0][jl][il] + b0;
      v.y = sR[0][1][jl][il] + sR[1][1][jl][il] + sR[2][1][jl][il] + sR[3][1][jl][il] + b1;
      *(float2*)(out + ((size_t)oi * ODIM + oj) * 2) = v;
    }
  }
}

extern "C" void kernel_launch(void* const* d_in, const int* in_sizes, int n_in,
                              void* d_out, int out_size, void* d_ws, size_t ws_size,
                              hipStream_t stream) {
  const float* X = (const float*)d_in[0];
  const float* W = (const float*)d_in[1];
  const float* b = (const float*)d_in[2];
  float* out = (float*)d_out;
  (void)in_sizes; (void)n_in; (void)out_size; (void)d_ws; (void)ws_size;

  hipLaunchKernelGGL(pcmd_fused, dim3(528), dim3(256), 0, stream, X, W, b, out);
}

// Round 2
// 74.528 us; speedup vs baseline: 1.0014x; 1.0014x over previous
//
#include <hip/hip_runtime.h>
#include <math.h>

#define D_DIM 1280
#define ODIM  510

typedef short bf16x8 __attribute__((ext_vector_type(8)));   // 8 bf16 = 4 VGPRs
typedef float f32x4  __attribute__((ext_vector_type(4)));

// pack two fp32 -> packed bf16 pair in ONE instruction (v_cvt_pk_bf16_f32, RNE).
// Replaces the 5-op bit-twiddle pkbf; gfx950-verified (guide T12/m240).
__device__ __forceinline__ unsigned pk2(float a, float b) {
  unsigned r;
  asm("v_cvt_pk_bf16_f32 %0, %1, %2" : "=v"(r) : "v"(a), "v"(b));
  return r;
}

union B8 { unsigned u[4]; bf16x8 v; };

// Fully fused: out[i,j,k] = sum_d X[i+1,d]*X[j+1,d]*Wp[d,k] + b[k]  (symmetrized
// diff term cancels). One block per upper-triangle 16x16 tile (528 blocks).
// Fragments gathered DIRECTLY from X (L2-resident, 2.6 MB) — no prep kernel,
// no workspace. 4 waves split K into quarters of 320; per K-step a lane loads
// its 32B row-chunk of X (A and B side) + 64B of W (quad-uniform -> broadcast),
// multiplies, packs bf16 via v_cvt_pk_bf16_f32, feeds 2 MFMAs.
__global__ __launch_bounds__(256, 2) void pcmd_fused(
    const float* __restrict__ X,        // [512][1280]
    const float* __restrict__ W,        // [2560][2] (first 1280 rows = Wp)
    const float* __restrict__ bias,     // [2]
    float* __restrict__ out)            // [510][510][2]
{
  __shared__ float sR[4][2][16][17];

  // upper-triangle decode: block t -> (bi, bj), bi <= bj
  const int t = (int)blockIdx.x;
  int bi = (int)((65.0 - sqrt(4225.0 - 8.0 * (double)t)) * 0.5);
  {
    int s0 = bi * 32 - (bi * (bi - 1)) / 2;
    if (t < s0) { --bi; }
    int s1 = (bi + 1) * 32 - ((bi + 1) * bi) / 2;
    if (t >= s1) { ++bi; }
  }
  const int start = bi * 32 - (bi * (bi - 1)) / 2;
  const int bj = bi + (t - start);

  const int tid  = threadIdx.x;
  const int lane = tid & 63;
  const int wv   = tid >> 6;            // K-quarter 0..3
  const int m    = lane & 15;
  const int quad = lane >> 4;

  // plane row r corresponds to X row r+1 (the [1:-1] crop). Rows >= 510 of the
  // 512-row tile space are store-guarded, so clamping to X row 511 is safe.
  const int rA = min(bi * 16 + m + 1, 511);
  const int rB = min(bj * 16 + m + 1, 511);
  const int kq = wv * 320 + quad * 8;   // this lane's k-base within its quarter
  const float* __restrict__ pa = X + (size_t)rA * D_DIM + kq;
  const float* __restrict__ pb = X + (size_t)rB * D_DIM + kq;
  const float* __restrict__ pw = W + 2 * kq;

  f32x4 acc0 = {0.f, 0.f, 0.f, 0.f};
  f32x4 acc1 = {0.f, 0.f, 0.f, 0.f};

  // depth-2 prefetch pipeline over the 10 K-steps of this wave's quarter
  float4 xa0[2], xa1[2], xb0[2], xb1[2], w0[2], w1[2], w2[2], w3[2];

  xa0[0] = *(const float4*)(pa + 0);   xa1[0] = *(const float4*)(pa + 4);
  xb0[0] = *(const float4*)(pb + 0);   xb1[0] = *(const float4*)(pb + 4);
  w0[0]  = *(const float4*)(pw + 0);   w1[0]  = *(const float4*)(pw + 4);
  w2[0]  = *(const float4*)(pw + 8);   w3[0]  = *(const float4*)(pw + 12);

  #pragma unroll
  for (int s = 0; s < 10; ++s) {
    const int cur = s & 1, nxt = cur ^ 1;
    if (s < 9) {
      const int o = (s + 1) * 32;       // compile-time after unroll -> imm offsets
      xa0[nxt] = *(const float4*)(pa + o);          xa1[nxt] = *(const float4*)(pa + o + 4);
      xb0[nxt] = *(const float4*)(pb + o);          xb1[nxt] = *(const float4*)(pb + o + 4);
      w0[nxt]  = *(const float4*)(pw + 2 * o);      w1[nxt]  = *(const float4*)(pw + 2 * o + 4);
      w2[nxt]  = *(const float4*)(pw + 2 * o + 8);  w3[nxt]  = *(const float4*)(pw + 2 * o + 12);
    }
    const float4 xA0 = xa0[cur], xA1 = xa1[cur];
    const float4 xB0 = xb0[cur], xB1 = xb1[cur];
    const float4 W0 = w0[cur], W1 = w1[cur], W2 = w2[cur], W3 = w3[cur];

    B8 fb, fa0, fa1;
    // B fragment: raw X (col side)
    fb.u[0] = pk2(xB0.x, xB0.y);  fb.u[1] = pk2(xB0.z, xB0.w);
    fb.u[2] = pk2(xB1.x, xB1.y);  fb.u[3] = pk2(xB1.z, xB1.w);
    // A fragments: X * Wp[:,0] and X * Wp[:,1] (row side)
    fa0.u[0] = pk2(xA0.x * W0.x, xA0.y * W0.z);  fa0.u[1] = pk2(xA0.z * W1.x, xA0.w * W1.z);
    fa0.u[2] = pk2(xA1.x * W2.x, xA1.y * W2.z);  fa0.u[3] = pk2(xA1.z * W3.x, xA1.w * W3.z);
    fa1.u[0] = pk2(xA0.x * W0.y, xA0.y * W0.w);  fa1.u[1] = pk2(xA0.z * W1.y, xA0.w * W1.w);
    fa1.u[2] = pk2(xA1.x * W2.y, xA1.y * W2.w);  fa1.u[3] = pk2(xA1.z * W3.y, xA1.w * W3.w);

    acc0 = __builtin_amdgcn_mfma_f32_16x16x32_bf16(fa0.v, fb.v, acc0, 0, 0, 0);
    acc1 = __builtin_amdgcn_mfma_f32_16x16x32_bf16(fa1.v, fb.v, acc1, 0, 0, 0);
  }

  // split-K reduce across the 4 waves via LDS
  #pragma unroll
  for (int r = 0; r < 4; ++r) {
    sR[wv][0][quad * 4 + r][m] = acc0[r];
    sR[wv][1][quad * 4 + r][m] = acc1[r];
  }
  __syncthreads();

  const float b0 = bias[0], b1 = bias[1];
  const int il = tid >> 4, jl = tid & 15;

  {
    const int oi = bi * 16 + il, oj = bj * 16 + jl;
    if (oi < ODIM && oj < ODIM) {
      float2 v;
      v.x = sR[0][0][il][jl] + sR[1][0][il][jl] + sR[2][0][il][jl] + sR[3][0][il][jl] + b0;
      v.y = sR[0][1][il][jl] + sR[1][1][il][jl] + sR[2][1][il][jl] + sR[3][1][il][jl] + b1;
      *(float2*)(out + ((size_t)oi * ODIM + oj) * 2) = v;
    }
  }
  if (bi != bj) {
    const int oi = bj * 16 + il, oj = bi * 16 + jl;
    if (oi < ODIM && oj < ODIM) {
      float2 v;
      v.x = sR[0][0][jl][il] + sR[1][0][jl][il] + sR[2][0][jl][il] + sR[3][0][jl][il] + b0;
      v.y = sR[0][1][jl][il] + sR[1][1][jl][il] + sR[2][1][jl][il] + sR[3][1][jl][il] + b1;
      *(float2*)(out + ((size_t)oi * ODIM + oj) * 2) = v;
    }
  }
}

extern "C" void kernel_launch(void* const* d_in, const int* in_sizes, int n_in,
                              void* d_out, int out_size, void* d_ws, size_t ws_size,
                              hipStream_t stream) {
  const float* X = (const float*)d_in[0];
  const float* W = (const float*)d_in[1];
  const float* b = (const float*)d_in[2];
  float* out = (float*)d_out;
  (void)in_sizes; (void)n_in; (void)out_size; (void)d_ws; (void)ws_size;

  hipLaunchKernelGGL(pcmd_fused, dim3(528), dim3(256), 0, stream, X, W, b, out);
}

// Round 3
// 69.877 us; speedup vs baseline: 1.0681x; 1.0666x over previous
//
#include <hip/hip_runtime.h>
#include <math.h>

#define D_DIM 1280
#define ODIM  510
#define KSTEPS 40           // 1280 / 32 granule-steps per plane row-block

typedef short bf16x8 __attribute__((ext_vector_type(8)));   // 8 bf16 = 4 VGPRs
typedef float f32x4  __attribute__((ext_vector_type(4)));

// pack two fp32 -> packed bf16 pair in ONE instruction (v_cvt_pk_bf16_f32, RNE).
// low16 = a, high16 = b — same packing order as the old 5-op pkbf; numerics
// validated in rounds 1-2 (absmax identical).
__device__ __forceinline__ unsigned pk2(float a, float b) {
  unsigned r;
  asm("v_cvt_pk_bf16_f32 %0, %1, %2" : "=v"(r) : "v"(a), "v"(b));
  return r;
}

// Prep v3: build bf16 planes in MFMA fragment order (granule (R,G,quad,m) holds
// plane[R*16+m][G*32+quad*8 ..+8], plane row r = X row r+1), routed through LDS
// so BOTH global sides are coalesced. vs round-0 prep: 256 blocks (32 row-blocks
// x 8 K-eighths — all CUs busy) and v_cvt_pk_bf16_f32 packing (VALU / 3).
__global__ __launch_bounds__(256, 1) void pcmd_prep(
    const float* __restrict__ X,        // [512][1280]
    const float* __restrict__ W,        // [2560][2] (first 1280 rows = Wp)
    unsigned short* __restrict__ Xbf,   // fragment-ordered planes
    unsigned short* __restrict__ A0,
    unsigned short* __restrict__ A1)
{
  __shared__ unsigned short sG[3][5][64][8];   // 15 KB

  const int R   = (int)blockIdx.x >> 3;   // row-block 0..31
  const int e   = (int)blockIdx.x & 7;    // K-eighth 0..7 (160 floats each)
  const int tid = threadIdx.x;

  // ---- phase 1: 320 tasks = 16 rows x 20 granules ----
  for (int task = tid; task < 320; task += 256) {
    const int lr = task / 20;             // local row 0..15
    const int gc = task - lr * 20;        // granule-in-eighth 0..19
    const int s = gc >> 2, quad = gc & 3;
    const int prow = R * 16 + lr;         // plane row
    uint4 vx = {0,0,0,0}, v0 = {0,0,0,0}, v1 = {0,0,0,0};
    if (prow <= 510) {                    // plane row <- X row prow+1; 511 stays zero
      const float* px = X + (size_t)(prow + 1) * D_DIM + e * 160 + gc * 8;
      float4 x0 = *(const float4*)px;
      float4 x1 = *(const float4*)(px + 4);
      const float* pw = W + 2 * (e * 160 + gc * 8);
      float4 w0 = *(const float4*)(pw +  0);
      float4 w1 = *(const float4*)(pw +  4);
      float4 w2 = *(const float4*)(pw +  8);
      float4 w3 = *(const float4*)(pw + 12);
      vx.x = pk2(x0.x, x0.y);             vx.y = pk2(x0.z, x0.w);
      vx.z = pk2(x1.x, x1.y);             vx.w = pk2(x1.z, x1.w);
      v0.x = pk2(x0.x*w0.x, x0.y*w0.z);   v0.y = pk2(x0.z*w1.x, x0.w*w1.z);
      v0.z = pk2(x1.x*w2.x, x1.y*w2.z);   v0.w = pk2(x1.z*w3.x, x1.w*w3.z);
      v1.x = pk2(x0.x*w0.y, x0.y*w0.w);   v1.y = pk2(x0.z*w1.y, x0.w*w1.w);
      v1.z = pk2(x1.x*w2.y, x1.y*w2.w);   v1.w = pk2(x1.z*w3.y, x1.w*w3.w);
    }
    const int swzl = quad * 16 + ((lr + quad + 4 * s) & 15);   // bank-spread rotation
    *(uint4*)&sG[0][s][swzl][0] = vx;
    *(uint4*)&sG[1][s][swzl][0] = v0;
    *(uint4*)&sG[2][s][swzl][0] = v1;
  }
  __syncthreads();

  // ---- phase 2: 320 granules, lane-linear coalesced global stores ----
  for (int g = tid; g < 320; g += 256) {
    const int s = g >> 6, l = g & 63;
    const int quad = l >> 4, m = l & 15;
    const int swzl = quad * 16 + ((m + quad + 4 * s) & 15);
    const size_t go = ((size_t)((R * KSTEPS + e * 5 + s) * 64) + l) * 8;
    *(uint4*)(Xbf + go) = *(const uint4*)&sG[0][s][swzl][0];
    *(uint4*)(A0  + go) = *(const uint4*)&sG[1][s][swzl][0];
    *(uint4*)(A1  + go) = *(const uint4*)&sG[2][s][swzl][0];
  }
}

// GEMM: verbatim the twice-verified round-0 kernel. Upper triangle of the 32x32
// tile grid, 528 blocks, 16x16 tiles; 4 waves split K into quarters; lane-linear
// fragment loads; LDS reduce; off-diagonal blocks also store the transposed tile.
__global__ __launch_bounds__(256, 2) void pcmd_gemm(
    const unsigned short* __restrict__ Xbf,
    const unsigned short* __restrict__ A0,
    const unsigned short* __restrict__ A1,
    const float* __restrict__ b,
    float* __restrict__ out)            // [510][510][2]
{
  __shared__ float sR[4][2][16][17];

  const int t = (int)blockIdx.x;        // 0..527
  int bi = (int)((65.0 - sqrt(4225.0 - 8.0 * (double)t)) * 0.5);
  {
    int s0 = bi * 32 - (bi * (bi - 1)) / 2;
    if (t < s0) { --bi; }
    int s1 = (bi + 1) * 32 - ((bi + 1) * bi) / 2;
    if (t >= s1) { ++bi; }
  }
  const int start = bi * 32 - (bi * (bi - 1)) / 2;
  const int bj = bi + (t - start);

  const int tid  = threadIdx.x;
  const int lane = tid & 63;
  const int wv   = tid >> 6;

  const unsigned short* pa0 = A0  + ((size_t)(bi * KSTEPS + wv * 10) * 64 + lane) * 8;
  const unsigned short* pa1 = A1  + ((size_t)(bi * KSTEPS + wv * 10) * 64 + lane) * 8;
  const unsigned short* pb  = Xbf + ((size_t)(bj * KSTEPS + wv * 10) * 64 + lane) * 8;

  bf16x8 ra0[4], ra1[4], rb[4];
  #pragma unroll
  for (int s = 0; s < 4; ++s) {
    ra0[s] = *(const bf16x8*)(pa0 + s * 512);
    ra1[s] = *(const bf16x8*)(pa1 + s * 512);
    rb[s]  = *(const bf16x8*)(pb  + s * 512);
  }

  f32x4 acc0 = {0.f, 0.f, 0.f, 0.f};
  f32x4 acc1 = {0.f, 0.f, 0.f, 0.f};

  #pragma unroll
  for (int s = 0; s < 10; ++s) {
    const int cur = s & 3;
    bf16x8 a0 = ra0[cur], a1 = ra1[cur], bb = rb[cur];
    if (s + 4 < 10) {
      ra0[cur] = *(const bf16x8*)(pa0 + (s + 4) * 512);
      ra1[cur] = *(const bf16x8*)(pa1 + (s + 4) * 512);
      rb[cur]  = *(const bf16x8*)(pb  + (s + 4) * 512);
    }
    acc0 = __builtin_amdgcn_mfma_f32_16x16x32_bf16(a0, bb, acc0, 0, 0, 0);
    acc1 = __builtin_amdgcn_mfma_f32_16x16x32_bf16(a1, bb, acc1, 0, 0, 0);
  }

  const int m = lane & 15, quad = lane >> 4;
  #pragma unroll
  for (int r = 0; r < 4; ++r) {
    sR[wv][0][quad * 4 + r][m] = acc0[r];
    sR[wv][1][quad * 4 + r][m] = acc1[r];
  }
  __syncthreads();

  const float b0 = b[0], b1 = b[1];
  const int il = tid >> 4, jl = tid & 15;

  {
    const int oi = bi * 16 + il, oj = bj * 16 + jl;
    if (oi < ODIM && oj < ODIM) {
      float2 v;
      v.x = sR[0][0][il][jl] + sR[1][0][il][jl] + sR[2][0][il][jl] + sR[3][0][il][jl] + b0;
      v.y = sR[0][1][il][jl] + sR[1][1][il][jl] + sR[2][1][il][jl] + sR[3][1][il][jl] + b1;
      *(float2*)(out + ((size_t)oi * ODIM + oj) * 2) = v;
    }
  }
  if (bi != bj) {
    const int oi = bj * 16 + il, oj = bi * 16 + jl;
    if (oi < ODIM && oj < ODIM) {
      float2 v;
      v.x = sR[0][0][jl][il] + sR[1][0][jl][il] + sR[2][0][jl][il] + sR[3][0][jl][il] + b0;
      v.y = sR[0][1][jl][il] + sR[1][1][jl][il] + sR[2][1][jl][il] + sR[3][1][jl][il] + b1;
      *(float2*)(out + ((size_t)oi * ODIM + oj) * 2) = v;
    }
  }
}

extern "C" void kernel_launch(void* const* d_in, const int* in_sizes, int n_in,
                              void* d_out, int out_size, void* d_ws, size_t ws_size,
                              hipStream_t stream) {
  const float* X = (const float*)d_in[0];
  const float* W = (const float*)d_in[1];
  const float* b = (const float*)d_in[2];
  float* out = (float*)d_out;
  (void)in_sizes; (void)n_in; (void)out_size; (void)ws_size;

  const size_t PLANE = (size_t)512 * D_DIM;        // elements per bf16 plane
  unsigned short* Xbf = (unsigned short*)d_ws;
  unsigned short* A0  = Xbf + PLANE;
  unsigned short* A1  = A0 + PLANE;

  hipLaunchKernelGGL(pcmd_prep, dim3(256), dim3(256), 0, stream, X, W, Xbf, A0, A1);
  hipLaunchKernelGGL(pcmd_gemm, dim3(528), dim3(256), 0, stream, Xbf, A0, A1, b, out);
}

// Round 4
// 65.736 us; speedup vs baseline: 1.1353x; 1.0630x over previous
//
#include <hip/hip_runtime.h>
#include <math.h>

#define D_DIM 1280
#define ODIM  510
#define KSTEPS 40           // 1280 / 32 granule-steps per plane row-block

typedef short bf16x8 __attribute__((ext_vector_type(8)));   // 8 bf16 = 4 VGPRs
typedef float f32x4  __attribute__((ext_vector_type(4)));

// pack two fp32 -> packed bf16 pair in ONE instruction (v_cvt_pk_bf16_f32, RNE).
// low16 = a, high16 = b; numerics validated rounds 1-3 (absmax identical).
__device__ __forceinline__ unsigned pk2(float a, float b) {
  unsigned r;
  asm("v_cvt_pk_bf16_f32 %0, %1, %2" : "=v"(r) : "v"(a), "v"(b));
  return r;
}

// Prep v4: identical plane bytes to v3, but 320-thread blocks so each phase is
// EXACTLY one task per thread (v3's 256 threads x 320 tasks had a second loop
// pass with 75% of lanes idle, twice). 256 blocks = 32 row-blocks x 8 K-eighths.
__global__ __launch_bounds__(320, 1) void pcmd_prep(
    const float* __restrict__ X,        // [512][1280]
    const float* __restrict__ W,        // [2560][2] (first 1280 rows = Wp)
    unsigned short* __restrict__ Xbf,   // fragment-ordered planes
    unsigned short* __restrict__ A0,
    unsigned short* __restrict__ A1)
{
  __shared__ unsigned short sG[3][5][64][8];   // 15 KB

  const int R   = (int)blockIdx.x >> 3;   // row-block 0..31
  const int e   = (int)blockIdx.x & 7;    // K-eighth 0..7 (160 floats each)
  const int tid = threadIdx.x;            // 0..319

  // ---- phase 1: 320 tasks = 16 rows x 20 granules, one per thread ----
  {
    const int lr = tid / 20;              // local row 0..15
    const int gc = tid - lr * 20;         // granule-in-eighth 0..19
    const int s = gc >> 2, quad = gc & 3;
    const int prow = R * 16 + lr;         // plane row
    uint4 vx = {0,0,0,0}, v0 = {0,0,0,0}, v1 = {0,0,0,0};
    if (prow <= 510) {                    // plane row <- X row prow+1; 511 stays zero
      const float* px = X + (size_t)(prow + 1) * D_DIM + e * 160 + gc * 8;
      float4 x0 = *(const float4*)px;
      float4 x1 = *(const float4*)(px + 4);
      const float* pw = W + 2 * (e * 160 + gc * 8);
      float4 w0 = *(const float4*)(pw +  0);
      float4 w1 = *(const float4*)(pw +  4);
      float4 w2 = *(const float4*)(pw +  8);
      float4 w3 = *(const float4*)(pw + 12);
      vx.x = pk2(x0.x, x0.y);             vx.y = pk2(x0.z, x0.w);
      vx.z = pk2(x1.x, x1.y);             vx.w = pk2(x1.z, x1.w);
      v0.x = pk2(x0.x*w0.x, x0.y*w0.z);   v0.y = pk2(x0.z*w1.x, x0.w*w1.z);
      v0.z = pk2(x1.x*w2.x, x1.y*w2.z);   v0.w = pk2(x1.z*w3.x, x1.w*w3.z);
      v1.x = pk2(x0.x*w0.y, x0.y*w0.w);   v1.y = pk2(x0.z*w1.y, x0.w*w1.w);
      v1.z = pk2(x1.x*w2.y, x1.y*w2.w);   v1.w = pk2(x1.z*w3.y, x1.w*w3.w);
    }
    const int swzl = quad * 16 + ((lr + quad + 4 * s) & 15);   // bank-spread rotation
    *(uint4*)&sG[0][s][swzl][0] = vx;
    *(uint4*)&sG[1][s][swzl][0] = v0;
    *(uint4*)&sG[2][s][swzl][0] = v1;
  }
  __syncthreads();

  // ---- phase 2: 320 granules, one per thread, lane-linear coalesced stores ----
  {
    const int s = tid >> 6, l = tid & 63;
    const int quad = l >> 4, m = l & 15;
    const int swzl = quad * 16 + ((m + quad + 4 * s) & 15);
    const size_t go = ((size_t)((R * KSTEPS + e * 5 + s) * 64) + l) * 8;
    *(uint4*)(Xbf + go) = *(const uint4*)&sG[0][s][swzl][0];
    *(uint4*)(A0  + go) = *(const uint4*)&sG[1][s][swzl][0];
    *(uint4*)(A1  + go) = *(const uint4*)&sG[2][s][swzl][0];
  }
}

// GEMM: verbatim round-0/3 kernel except for an XCD-aware block swizzle:
// 528 blocks = 8 XCDs x 66, and consecutive logical tiles t share bi (same
// A-panels), so chunking t ranges onto XCDs makes A-panels L2-resident.
// 528 % 8 == 0 -> the simple swizzle is bijective.
__global__ __launch_bounds__(256, 2) void pcmd_gemm(
    const unsigned short* __restrict__ Xbf,
    const unsigned short* __restrict__ A0,
    const unsigned short* __restrict__ A1,
    const float* __restrict__ b,
    float* __restrict__ out)            // [510][510][2]
{
  __shared__ float sR[4][2][16][17];

  // XCD swizzle: hardware round-robins blockIdx across 8 XCDs; remap so each
  // XCD owns a contiguous chunk of 66 tiles (which share bi / A-panels).
  const int t = ((int)blockIdx.x % 8) * 66 + (int)blockIdx.x / 8;   // 0..527
  int bi = (int)((65.0 - sqrt(4225.0 - 8.0 * (double)t)) * 0.5);
  {
    int s0 = bi * 32 - (bi * (bi - 1)) / 2;
    if (t < s0) { --bi; }
    int s1 = (bi + 1) * 32 - ((bi + 1) * bi) / 2;
    if (t >= s1) { ++bi; }
  }
  const int start = bi * 32 - (bi * (bi - 1)) / 2;
  const int bj = bi + (t - start);

  const int tid  = threadIdx.x;
  const int lane = tid & 63;
  const int wv   = tid >> 6;

  const unsigned short* pa0 = A0  + ((size_t)(bi * KSTEPS + wv * 10) * 64 + lane) * 8;
  const unsigned short* pa1 = A1  + ((size_t)(bi * KSTEPS + wv * 10) * 64 + lane) * 8;
  const unsigned short* pb  = Xbf + ((size_t)(bj * KSTEPS + wv * 10) * 64 + lane) * 8;

  bf16x8 ra0[4], ra1[4], rb[4];
  #pragma unroll
  for (int s = 0; s < 4; ++s) {
    ra0[s] = *(const bf16x8*)(pa0 + s * 512);
    ra1[s] = *(const bf16x8*)(pa1 + s * 512);
    rb[s]  = *(const bf16x8*)(pb  + s * 512);
  }

  f32x4 acc0 = {0.f, 0.f, 0.f, 0.f};
  f32x4 acc1 = {0.f, 0.f, 0.f, 0.f};

  #pragma unroll
  for (int s = 0; s < 10; ++s) {
    const int cur = s & 3;
    bf16x8 a0 = ra0[cur], a1 = ra1[cur], bb = rb[cur];
    if (s + 4 < 10) {
      ra0[cur] = *(const bf16x8*)(pa0 + (s + 4) * 512);
      ra1[cur] = *(const bf16x8*)(pa1 + (s + 4) * 512);
      rb[cur]  = *(const bf16x8*)(pb  + (s + 4) * 512);
    }
    acc0 = __builtin_amdgcn_mfma_f32_16x16x32_bf16(a0, bb, acc0, 0, 0, 0);
    acc1 = __builtin_amdgcn_mfma_f32_16x16x32_bf16(a1, bb, acc1, 0, 0, 0);
  }

  const int m = lane & 15, quad = lane >> 4;
  #pragma unroll
  for (int r = 0; r < 4; ++r) {
    sR[wv][0][quad * 4 + r][m] = acc0[r];
    sR[wv][1][quad * 4 + r][m] = acc1[r];
  }
  __syncthreads();

  const float b0 = b[0], b1 = b[1];
  const int il = tid >> 4, jl = tid & 15;

  {
    const int oi = bi * 16 + il, oj = bj * 16 + jl;
    if (oi < ODIM && oj < ODIM) {
      float2 v;
      v.x = sR[0][0][il][jl] + sR[1][0][il][jl] + sR[2][0][il][jl] + sR[3][0][il][jl] + b0;
      v.y = sR[0][1][il][jl] + sR[1][1][il][jl] + sR[2][1][il][jl] + sR[3][1][il][jl] + b1;
      *(float2*)(out + ((size_t)oi * ODIM + oj) * 2) = v;
    }
  }
  if (bi != bj) {
    const int oi = bj * 16 + il, oj = bi * 16 + jl;
    if (oi < ODIM && oj < ODIM) {
      float2 v;
      v.x = sR[0][0][jl][il] + sR[1][0][jl][il] + sR[2][0][jl][il] + sR[3][0][jl][il] + b0;
      v.y = sR[0][1][jl][il] + sR[1][1][jl][il] + sR[2][1][jl][il] + sR[3][1][jl][il] + b1;
      *(float2*)(out + ((size_t)oi * ODIM + oj) * 2) = v;
    }
  }
}

extern "C" void kernel_launch(void* const* d_in, const int* in_sizes, int n_in,
                              void* d_out, int out_size, void* d_ws, size_t ws_size,
                              hipStream_t stream) {
  const float* X = (const float*)d_in[0];
  const float* W = (const float*)d_in[1];
  const float* b = (const float*)d_in[2];
  float* out = (float*)d_out;
  (void)in_sizes; (void)n_in; (void)out_size; (void)ws_size;

  const size_t PLANE = (size_t)512 * D_DIM;        // elements per bf16 plane
  unsigned short* Xbf = (unsigned short*)d_ws;
  unsigned short* A0  = Xbf + PLANE;
  unsigned short* A1  = A0 + PLANE;

  hipLaunchKernelGGL(pcmd_prep, dim3(256), dim3(320), 0, stream, X, W, Xbf, A0, A1);
  hipLaunchKernelGGL(pcmd_gemm, dim3(528), dim3(256), 0, stream, Xbf, A0, A1, b, out);
}